// Round 4
// baseline (1155.164 us; speedup 1.0000x reference)
//
#include <hip/hip_runtime.h>
#include <math.h>

#define DIM 7168
#define NE 256
#define NG 8
#define GSZ 32
#define TOPG 4
#define TOPK_N 8
#define BM 32
#define BK 16
#define NTHR 256
#define NCHUNK (DIM / BK)   // 448

__global__ __launch_bounds__(NTHR) void gate_kernel(
    const float* __restrict__ x, const float* __restrict__ w,
    const float* __restrict__ bias, float* __restrict__ out, int n)
{
    // 64 KB LDS, union:
    //   staging: w2[2][16][256] f32 (32KB) + x2[2][16][34] f64 (8.7KB)
    //   overlay: sc[256][32] f64 (64KB)  -- transposed: sc[e][row]
    __shared__ __align__(16) char smem[65536];
    float  (*w2)[BK][NE]  = reinterpret_cast<float(*)[BK][NE]>(smem);
    double (*x2)[BK][34]  = reinterpret_cast<double(*)[BK][34]>(smem + 32768);
    double (*sc)[BM]      = reinterpret_cast<double(*)[BM]>(smem);

    const int t    = threadIdx.x;
    const int row0 = blockIdx.x * BM;

    // ---- staging assignment ----
    const int  we   = t;                 // expert whose 16 k-values this thread stages
    const long wrow = (long)we * DIM;
    const int  sxr  = t >> 3;            // 0..31
    const int  sxk  = (t & 7) * 2;       // even k within chunk
    int rr = row0 + sxr; if (rr > n - 1) rr = n - 1;
    const long xoff = (long)rr * DIM + sxk;

    // ---- compute assignment: 4 rows x 8 experts per thread ----
    const int rg    = t >> 5;            // 0..7
    const int rbase = 4 * rg;
    const int le    = t & 31;
    const int eA    = 4 * le;            // experts eA..eA+3
    const int eB    = 128 + 4 * le;      // experts eB..eB+3

    double acc[4][8];
#pragma unroll
    for (int i = 0; i < 4; ++i)
#pragma unroll
        for (int j = 0; j < 8; ++j) acc[i][j] = 0.0;

    // prefetch chunk 0
    float4 wr0 = *(const float4*)&w[wrow + 0];
    float4 wr1 = *(const float4*)&w[wrow + 4];
    float4 wr2 = *(const float4*)&w[wrow + 8];
    float4 wr3 = *(const float4*)&w[wrow + 12];
    float2 xr  = *(const float2*)&x[xoff];

    for (int c = 0; c < NCHUNK; ++c) {
        const int b = c & 1;
        // ---- write staged chunk c into buffer b ----
        {
            const float* f0 = reinterpret_cast<const float*>(&wr0);
            const float* f1 = reinterpret_cast<const float*>(&wr1);
            const float* f2 = reinterpret_cast<const float*>(&wr2);
            const float* f3 = reinterpret_cast<const float*>(&wr3);
#pragma unroll
            for (int q = 0; q < 4; ++q) {
                w2[b][q][we]      = f0[q];
                w2[b][4 + q][we]  = f1[q];
                w2[b][8 + q][we]  = f2[q];
                w2[b][12 + q][we] = f3[q];
            }
            x2[b][sxk][sxr]     = (double)xr.x;
            x2[b][sxk + 1][sxr] = (double)xr.y;
        }
        // ---- issue chunk c+1 global loads ----
        {
            const int  cn = (c + 1 < NCHUNK) ? (c + 1) : c;
            const long k0 = (long)cn * BK;
            wr0 = *(const float4*)&w[wrow + k0];
            wr1 = *(const float4*)&w[wrow + k0 + 4];
            wr2 = *(const float4*)&w[wrow + k0 + 8];
            wr3 = *(const float4*)&w[wrow + k0 + 12];
            xr  = *(const float2*)&x[xoff + k0];
        }
        __syncthreads();   // buffer b complete; prev buffer's readers done
        // ---- compute from buffer b ----
#pragma unroll
        for (int kk = 0; kk < BK; ++kk) {
            const double x0 = x2[b][kk][rbase + 0];
            const double x1 = x2[b][kk][rbase + 1];
            const double x2v = x2[b][kk][rbase + 2];
            const double x3 = x2[b][kk][rbase + 3];
            const float4 wa = *(const float4*)&w2[b][kk][eA];
            const float4 wb = *(const float4*)&w2[b][kk][eB];
            const double wd[8] = {(double)wa.x, (double)wa.y, (double)wa.z, (double)wa.w,
                                  (double)wb.x, (double)wb.y, (double)wb.z, (double)wb.w};
#pragma unroll
            for (int j = 0; j < 8; ++j) {
                acc[0][j] = fma(x0,  wd[j], acc[0][j]);
                acc[1][j] = fma(x1,  wd[j], acc[1][j]);
                acc[2][j] = fma(x2v, wd[j], acc[2][j]);
                acc[3][j] = fma(x3,  wd[j], acc[3][j]);
            }
        }
    }

    __syncthreads();   // done with staging buffers; overlay sc
#pragma unroll
    for (int i = 0; i < 4; ++i)
#pragma unroll
        for (int j = 0; j < 4; ++j) {
            sc[eA + j][rbase + i] = acc[i][j];
            sc[eB + j][rbase + i] = acc[i][4 + j];
        }
    __syncthreads();

    // ---- routing: round-1/3 verbatim semantics, sc transposed [e][row] ----
    if (t < BM) {
        const int row = row0 + t;
        if (row < n) {
            double zmax = -1e300;
            for (int e = 0; e < NE; ++e) zmax = fmax(zmax, sc[e][t]);
            double Z = 0.0;
            for (int e = 0; e < NE; ++e) {
                double p = exp(sc[e][t] - zmax);
                sc[e][t] = p;           // column t private to this thread
                Z += p;
            }
            const double invZ = 1.0 / Z;

            double gs[NG];
            for (int g = 0; g < NG; ++g) {
                double m1 = -1e300, m2 = -1e300;
                for (int i = 0; i < GSZ; ++i) {
                    double v = sc[g * GSZ + i][t] * invZ + (double)bias[g * GSZ + i];
                    if (v > m1) { m2 = m1; m1 = v; }
                    else if (v > m2) { m2 = v; }
                }
                gs[g] = m1 + m2;
            }
            unsigned keep = 0;
            for (int tt = 0; tt < TOPG; ++tt) {
                double best = -1e300; int bg = 0;
                for (int g = 0; g < NG; ++g)
                    if (!((keep >> g) & 1u) && gs[g] > best) { best = gs[g]; bg = g; }
                keep |= 1u << bg;
            }
            unsigned long long tk[4] = {0ull, 0ull, 0ull, 0ull};
            float* out_w = out;
            float* out_i = out + (size_t)n * TOPK_N;
            for (int pp = 0; pp < TOPK_N; ++pp) {
                double best = -1e300; int be = 0;
                for (int e = 0; e < NE; ++e) {
                    if (!((keep >> (e >> 5)) & 1u)) continue;
                    if ((tk[e >> 6] >> (e & 63)) & 1ull) continue;
                    double s = sc[e][t] * invZ + (double)bias[e];
                    if (s > best) { best = s; be = e; }
                }
                tk[be >> 6] |= 1ull << (be & 63);
                out_w[(size_t)row * TOPK_N + pp] = (float)(sc[be][t] * invZ * 2.5);
                out_i[(size_t)row * TOPK_N + pp] = (float)be;
            }
        }
    }
}

extern "C" void kernel_launch(void* const* d_in, const int* in_sizes, int n_in,
                              void* d_out, int out_size, void* d_ws, size_t ws_size,
                              hipStream_t stream) {
    const float* x  = (const float*)d_in[0];
    const float* w  = (const float*)d_in[1];
    const float* b  = (const float*)d_in[2];
    float* out      = (float*)d_out;
    const int n     = in_sizes[0] / DIM;
    const int nblk  = (n + BM - 1) / BM;
    gate_kernel<<<nblk, NTHR, 0, stream>>>(x, w, b, out, n);
}

// Round 5
// 979.280 us; speedup vs baseline: 1.1796x; 1.1796x over previous
//
#include <hip/hip_runtime.h>
#include <math.h>

#define DIM 7168
#define NE 256
#define NG 8
#define GSZ 32
#define TOPG 4
#define TOPK_N 8
#define BM 32
#define BK 16
#define NTHR 512
#define NCHUNK (DIM / BK)   // 448

__global__ __launch_bounds__(NTHR) void gate_kernel(
    const float* __restrict__ x, const float* __restrict__ w,
    const float* __restrict__ bias, float* __restrict__ out, int n)
{
    // 64 KB LDS union:
    //   staging: w_t[16][256] f64 (32 KB) + x_s[16][34] f64 (4.3 KB)
    //   overlay: sc[256][32] f64 (64 KB), written only after GEMM done
    __shared__ __align__(16) char smem[65536];
    double (*w_t)[NE] = reinterpret_cast<double(*)[NE]>(smem);          // [16][256]
    double (*x_s)[34] = reinterpret_cast<double(*)[34]>(smem + 32768);  // [16][34]
    double (*sc)[BM]  = reinterpret_cast<double(*)[BM]>(smem);          // overlay [256][32]

    const int t    = threadIdx.x;
    const int lane = t & 63;
    const int wv   = t >> 6;          // wave 0..7 -> rows 4wv..4wv+3
    const int row0 = blockIdx.x * BM;

    // ---- staging assignment ----
    const int  we  = t & 255;         // expert staged by this thread
    const int  wh  = (t >> 8) * 8;    // k-half 0 or 8
    const long wrow = (long)we * DIM + wh;
    const int  sxr = t >> 2;          // x row (t<128)
    const int  sxk = (t & 3) * 4;     // x k quad
    int rr = row0 + sxr; if (rr > n - 1) rr = n - 1;
    const long xoff = (long)rr * DIM + sxk;

    // ---- compute assignment: rows 4wv..4wv+3, experts {2l,2l+1,128+2l,129+2l} ----
    const int eA = 2 * lane;          // experts eA, eA+1
    const int eB = 128 + 2 * lane;    // experts eB, eB+1

    double acc[4][4];                 // [row i][j: 0,1->eA+j ; 2,3->eB+j-2]
#pragma unroll
    for (int i = 0; i < 4; ++i)
#pragma unroll
        for (int j = 0; j < 4; ++j) acc[i][j] = 0.0;

    // prefetch chunk 0
    float4 wa = *(const float4*)&w[wrow];
    float4 wb = *(const float4*)&w[wrow + 4];
    float4 xv = {0.f, 0.f, 0.f, 0.f};
    if (t < 128) xv = *(const float4*)&x[xoff];

    for (int c = 0; c < NCHUNK; ++c) {
        __syncthreads();   // all waves done reading previous chunk's LDS
        // ---- stage chunk c: f32 regs -> f64 LDS (cvt once here, not per use) ----
        {
            const float* fa = reinterpret_cast<const float*>(&wa);
            const float* fb = reinterpret_cast<const float*>(&wb);
#pragma unroll
            for (int q = 0; q < 4; ++q) {
                w_t[wh + q][we]     = (double)fa[q];
                w_t[wh + 4 + q][we] = (double)fb[q];
            }
            if (t < 128) {
                const float* fx = reinterpret_cast<const float*>(&xv);
#pragma unroll
                for (int q = 0; q < 4; ++q) x_s[sxk + q][sxr] = (double)fx[q];
            }
        }
        // ---- issue chunk c+1 global loads (in flight under compute) ----
        {
            const int  cn = (c + 1 < NCHUNK) ? (c + 1) : c;
            const long k0 = (long)cn * BK;
            wa = *(const float4*)&w[wrow + k0];
            wb = *(const float4*)&w[wrow + k0 + 4];
            if (t < 128) xv = *(const float4*)&x[xoff + k0];
        }
        __syncthreads();   // staged LDS visible
        // ---- compute ----
#pragma unroll
        for (int kk = 0; kk < BK; ++kk) {
            const double2 xu0 = *reinterpret_cast<const double2*>(&x_s[kk][4 * wv]);     // uniform
            const double2 xu1 = *reinterpret_cast<const double2*>(&x_s[kk][4 * wv + 2]); // uniform
            const double2 w0  = *reinterpret_cast<const double2*>(&w_t[kk][eA]);         // contig b128
            const double2 w1  = *reinterpret_cast<const double2*>(&w_t[kk][eB]);         // contig b128
            const double xr[4] = {xu0.x, xu0.y, xu1.x, xu1.y};
            const double wd[4] = {w0.x, w0.y, w1.x, w1.y};
#pragma unroll
            for (int i = 0; i < 4; ++i)
#pragma unroll
                for (int j = 0; j < 4; ++j)
                    acc[i][j] = fma(xr[i], wd[j], acc[i][j]);
        }
    }

    __syncthreads();   // done with staging; overlay sc
#pragma unroll
    for (int j = 0; j < 4; ++j) {
        const int e = (j < 2) ? (eA + j) : (eB + j - 2);
        double2 lo; lo.x = acc[0][j]; lo.y = acc[1][j];
        double2 hi; hi.x = acc[2][j]; hi.y = acc[3][j];
        *reinterpret_cast<double2*>(&sc[e][4 * wv])     = lo;
        *reinterpret_cast<double2*>(&sc[e][4 * wv + 2]) = hi;
    }
    __syncthreads();

    // ---- routing: verbatim round-4 (serial per row, sc transposed [e][row]) ----
    if (t < BM) {
        const int row = row0 + t;
        if (row < n) {
            double zmax = -1e300;
            for (int e = 0; e < NE; ++e) zmax = fmax(zmax, sc[e][t]);
            double Z = 0.0;
            for (int e = 0; e < NE; ++e) {
                double p = exp(sc[e][t] - zmax);
                sc[e][t] = p;           // column t private to this thread
                Z += p;
            }
            const double invZ = 1.0 / Z;

            double gs[NG];
            for (int g = 0; g < NG; ++g) {
                double m1 = -1e300, m2 = -1e300;
                for (int i = 0; i < GSZ; ++i) {
                    double v = sc[g * GSZ + i][t] * invZ + (double)bias[g * GSZ + i];
                    if (v > m1) { m2 = m1; m1 = v; }
                    else if (v > m2) { m2 = v; }
                }
                gs[g] = m1 + m2;
            }
            unsigned keep = 0;
            for (int tt = 0; tt < TOPG; ++tt) {
                double best = -1e300; int bg = 0;
                for (int g = 0; g < NG; ++g)
                    if (!((keep >> g) & 1u) && gs[g] > best) { best = gs[g]; bg = g; }
                keep |= 1u << bg;
            }
            unsigned long long tk[4] = {0ull, 0ull, 0ull, 0ull};
            float* out_w = out;
            float* out_i = out + (size_t)n * TOPK_N;
            for (int pp = 0; pp < TOPK_N; ++pp) {
                double best = -1e300; int be = 0;
                for (int e = 0; e < NE; ++e) {
                    if (!((keep >> (e >> 5)) & 1u)) continue;
                    if ((tk[e >> 6] >> (e & 63)) & 1ull) continue;
                    double s = sc[e][t] * invZ + (double)bias[e];
                    if (s > best) { best = s; be = e; }
                }
                tk[be >> 6] |= 1ull << (be & 63);
                out_w[(size_t)row * TOPK_N + pp] = (float)(sc[be][t] * invZ * 2.5);
                out_i[(size_t)row * TOPK_N + pp] = (float)be;
            }
        }
    }
}

extern "C" void kernel_launch(void* const* d_in, const int* in_sizes, int n_in,
                              void* d_out, int out_size, void* d_ws, size_t ws_size,
                              hipStream_t stream) {
    const float* x  = (const float*)d_in[0];
    const float* w  = (const float*)d_in[1];
    const float* b  = (const float*)d_in[2];
    float* out      = (float*)d_out;
    const int n     = in_sizes[0] / DIM;
    const int nblk  = (n + BM - 1) / BM;
    gate_kernel<<<nblk, NTHR, 0, stream>>>(x, w, b, out, n);
}